// Round 1
// baseline (313.300 us; speedup 1.0000x reference)
//
#include <hip/hip_runtime.h>

#define HH 128
#define WW 128
#define CIN 64
#define COUT 64
#define KTAPS 9
#define HW (HH*WW)

// Transpose weight (Cout,Cin,3,3) -> wt[k][c][co] for coalesced LDS staging.
__global__ void wtrans_kernel(const float* __restrict__ w, float* __restrict__ wt) {
    int i = blockIdx.x * 256 + threadIdx.x;
    if (i < COUT * CIN * KTAPS) {
        int co = i & 63;
        int c  = (i >> 6) & 63;
        int k  = i >> 12;
        wt[i] = w[co * (CIN * KTAPS) + c * KTAPS + k];
    }
}

// One block: 64 pixels (half row) x all 64 Cout. 256 threads.
__global__ __launch_bounds__(256, 2) void deform_main(
    const float* __restrict__ x,     // [B,64,128,128]
    const float* __restrict__ off,   // [B,18,128,128]
    const float* __restrict__ msk,   // [B,9,128,128]
    const float* __restrict__ wsrc,  // wt[k][c][co] if use_wt else raw weight
    const float* __restrict__ bias,  // [64]
    float* __restrict__ out,         // [B,64,128,128]
    int use_wt)
{
    __shared__ float s_tile[64 * 64];   // [c][pix]
    __shared__ float w_t[64 * 64];      // [c][co]
    __shared__ float4 mw[KTAPS * 64];   // bilinear weights (mask+valid folded)
    __shared__ int4   mo[KTAPS * 64];   // clamped corner word-offsets in plane

    const int t   = threadIdx.x;
    const int bid = blockIdx.x;
    const int b   = bid >> 8;          // 256 blocks per batch (128 rows x 2 tiles)
    const int rem = bid & 255;
    const int ho  = rem >> 1;
    const int wo0 = (rem & 1) << 6;

    // ---- per-(tap,pixel) metadata ----
    for (int i = t; i < KTAPS * 64; i += 256) {
        int p = i & 63;
        int k = i >> 6;
        int wo = wo0 + p;
        int obase = ((b * 18 + 2 * k) * HH + ho) * WW + wo;
        float oy = off[obase];
        float ox = off[obase + HW];
        float m  = msk[((b * 9 + k) * HH + ho) * WW + wo];
        float py = oy + (float)(k / 3) + (float)(ho - 1);
        float px = ox + (float)(k % 3) + (float)(wo - 1);
        float fy = floorf(py), fx = floorf(px);
        float ly = py - fy,    lx = px - fx;
        int y0 = (int)fy, x0 = (int)fx;
        int y1 = y0 + 1,  x1 = x0 + 1;
        float vy0 = (y0 >= 0 && y0 < HH) ? 1.f : 0.f;
        float vy1 = (y1 >= 0 && y1 < HH) ? 1.f : 0.f;
        float vx0 = (x0 >= 0 && x0 < WW) ? 1.f : 0.f;
        float vx1 = (x1 >= 0 && x1 < WW) ? 1.f : 0.f;
        float w00 = (1.f - ly) * (1.f - lx) * m * vy0 * vx0;
        float w01 = (1.f - ly) * lx         * m * vy0 * vx1;
        float w10 = ly         * (1.f - lx) * m * vy1 * vx0;
        float w11 = ly         * lx         * m * vy1 * vx1;
        int yc0 = min(max(y0, 0), HH - 1), yc1 = min(max(y1, 0), HH - 1);
        int xc0 = min(max(x0, 0), WW - 1), xc1 = min(max(x1, 0), WW - 1);
        mw[i] = make_float4(w00, w01, w10, w11);
        mo[i] = make_int4(yc0 * WW + xc0, yc0 * WW + xc1,
                          yc1 * WW + xc0, yc1 * WW + xc1);
    }

    // thread owns pixels tp..tp+3 (consecutive) x couts tc..tc+3
    const int tp = (t & 15) << 2;
    const int tc = (t >> 4) << 2;
    float acc[4][4];
    #pragma unroll
    for (int ci = 0; ci < 4; ++ci) {
        float bv = bias[tc + ci];
        #pragma unroll
        for (int pi = 0; pi < 4; ++pi) acc[pi][ci] = bv;
    }

    const float* xb = x + (size_t)b * CIN * HW;
    const int p  = t & 63;
    const int c0 = (t >> 6) << 4;

    for (int k = 0; k < KTAPS; ++k) {
        __syncthreads();   // meta ready / previous tiles consumed
        // stage weights for this tap
        if (use_wt) {
            #pragma unroll
            for (int j = 0; j < 16; ++j) {
                int i = t + j * 256;
                w_t[i] = wsrc[k * 4096 + i];
            }
        } else {
            #pragma unroll
            for (int j = 0; j < 16; ++j) {
                int i = t + j * 256;
                int c = i >> 6, co = i & 63;
                w_t[i] = wsrc[co * (CIN * KTAPS) + c * KTAPS + k];
            }
        }
        // sampling: 16 channels per thread for this thread's pixel
        {
            float4 wv = mw[k * 64 + p];
            int4   ov = mo[k * 64 + p];
            const float* pc = xb + (size_t)c0 * HW;
            #pragma unroll 8
            for (int i = 0; i < 16; ++i) {
                float v = wv.x * pc[ov.x] + wv.y * pc[ov.y]
                        + wv.z * pc[ov.z] + wv.w * pc[ov.w];
                s_tile[(c0 + i) * 64 + p] = v;
                pc += HW;
            }
        }
        __syncthreads();
        // GEMM: acc[pi][ci] += s[c][tp+pi] * w[c][tc+ci]
        #pragma unroll 4
        for (int c = 0; c < 64; ++c) {
            float4 sv4 = *(const float4*)&s_tile[c * 64 + tp];
            float4 wv4 = *(const float4*)&w_t[c * 64 + tc];
            float sv[4] = {sv4.x, sv4.y, sv4.z, sv4.w};
            float wv[4] = {wv4.x, wv4.y, wv4.z, wv4.w};
            #pragma unroll
            for (int pi = 0; pi < 4; ++pi)
                #pragma unroll
                for (int ci = 0; ci < 4; ++ci)
                    acc[pi][ci] = fmaf(sv[pi], wv[ci], acc[pi][ci]);
        }
    }

    // epilogue: coalesced float4 stores (4 consecutive pixels per store)
    float* ob = out + (size_t)b * COUT * HW + (size_t)ho * WW + wo0;
    #pragma unroll
    for (int ci = 0; ci < 4; ++ci) {
        float4 v = make_float4(acc[0][ci], acc[1][ci], acc[2][ci], acc[3][ci]);
        *(float4*)&ob[(size_t)(tc + ci) * HW + tp] = v;
    }
}

extern "C" void kernel_launch(void* const* d_in, const int* in_sizes, int n_in,
                              void* d_out, int out_size, void* d_ws, size_t ws_size,
                              hipStream_t stream) {
    const float* x    = (const float*)d_in[0];
    const float* off  = (const float*)d_in[1];
    const float* msk  = (const float*)d_in[2];
    const float* w    = (const float*)d_in[3];
    const float* bias = (const float*)d_in[4];
    float* out = (float*)d_out;

    int use_wt = (d_ws != nullptr && ws_size >= (size_t)(COUT * CIN * KTAPS) * sizeof(float)) ? 1 : 0;
    const float* wsrc = w;
    if (use_wt) {
        wtrans_kernel<<<(COUT * CIN * KTAPS + 255) / 256, 256, 0, stream>>>(w, (float*)d_ws);
        wsrc = (const float*)d_ws;
    }
    deform_main<<<8 * 128 * 2, 256, 0, stream>>>(x, off, msk, wsrc, bias, out, use_wt);
}

// Round 2
// 215.985 us; speedup vs baseline: 1.4506x; 1.4506x over previous
//
#include <hip/hip_runtime.h>
#include <hip/hip_bf16.h>

#define HH 128
#define WW 128
#define HW (HH*WW)

typedef __attribute__((ext_vector_type(8))) short short8;
typedef __attribute__((ext_vector_type(4))) float f32x4;

static __device__ __forceinline__ unsigned short f2bf(float f) {
    // round-to-nearest-even fp32 -> bf16 (finite inputs)
    unsigned int u = __float_as_uint(f);
    u += 0x7fffu + ((u >> 16) & 1u);
    return (unsigned short)(u >> 16);
}

// Pack weight (Cout=64, Cin=64, 3, 3) fp32 -> bf16 B-fragment layout:
// wt[tap][kf][wave][lane][e], value = w[co = 16*wave + (lane&15)][c = 32*kf + (lane>>4)*8 + e][tap]
__global__ void wtrans_kernel(const float* __restrict__ w, unsigned short* __restrict__ wt) {
    int i = blockIdx.x * 256 + threadIdx.x;
    if (i < 9 * 2 * 4 * 64 * 8) {
        int e  = i & 7;
        int l  = (i >> 3) & 63;
        int wv = (i >> 9) & 3;
        int kf = (i >> 11) & 1;
        int k  = i >> 12;
        int co = wv * 16 + (l & 15);
        int c  = kf * 32 + (l >> 4) * 8 + e;
        wt[i] = f2bf(w[(co * 64 + c) * 9 + k]);
    }
}

// One block: 64 pixels (half row) x 64 couts, 256 threads (4 waves).
// Wave w: samples channels [16w,16w+16) for all 64 px; MFMAs couts [16w,16w+16).
__global__ __launch_bounds__(256, 4) void deform_main(
    const float* __restrict__ x,     // [8,64,128,128]
    const float* __restrict__ off,   // [8,18,128,128]
    const float* __restrict__ msk,   // [8,9,128,128]
    const float* __restrict__ wraw,  // raw fp32 weight (fallback)
    const unsigned short* __restrict__ wt,  // packed bf16 fragments
    const float* __restrict__ bias,  // [64]
    float* __restrict__ out,         // [8,64,128,128]
    int use_wt)
{
    __shared__ unsigned short s_tile[2][64][68];          // bf16 sampled [px][ch], 136B rows
    __shared__ __align__(16) unsigned char meta_mem[18432];
    float4* mwS = (float4*)meta_mem;                      // [9][64] bilinear weights
    int4*   moS = (int4*)(meta_mem + 9216);               // [9][64] corner offsets
    float*  out_t = (float*)meta_mem;                     // epilogue overlay [64][68]

    const int t   = threadIdx.x;
    const int bid = blockIdx.x;
    const int b   = bid & 7;            // image <-> XCD affinity
    const int rem = bid >> 3;
    const int ho  = rem >> 1;
    const int wo0 = (rem & 1) << 6;
    const int l   = t & 63;
    const int wv_id = __builtin_amdgcn_readfirstlane(t >> 6);
    const int c0  = wv_id << 4;          // sampling channel group
    const int cb  = wv_id << 4;          // mfma cout group

    // ---- weight fragments: rotating 2-tap prefetch in registers ----
    short8 wtf[2][2];
    #pragma unroll
    for (int kf = 0; kf < 2; ++kf) {
        if (use_wt) {
            wtf[0][kf] = *(const short8*)(wt + ((((0 * 2 + kf) * 4 + wv_id) * 64 + l) << 3));
        } else {
            short8 f;
            int co = cb + (l & 15);
            int cbase = kf * 32 + (l >> 4) * 8;
            #pragma unroll
            for (int e = 0; e < 8; ++e) f[e] = (short)f2bf(wraw[(co * 64 + cbase + e) * 9 + 0]);
            wtf[0][kf] = f;
        }
    }

    // ---- per-(tap,pixel) metadata for all 9 taps ----
    for (int i = t; i < 9 * 64; i += 256) {
        int p = i & 63;
        int k = i >> 6;
        int wo = wo0 + p;
        int obase = ((b * 18 + 2 * k) * HH + ho) * WW + wo;
        float oy = off[obase];
        float ox = off[obase + HW];
        float m  = msk[((b * 9 + k) * HH + ho) * WW + wo];
        float py = oy + (float)(k / 3) + (float)(ho - 1);
        float px = ox + (float)(k % 3) + (float)(wo - 1);
        float fy = floorf(py), fx = floorf(px);
        float ly = py - fy,    lx = px - fx;
        int y0 = (int)fy, x0 = (int)fx;
        int y1 = y0 + 1,  x1 = x0 + 1;
        float vy0 = (y0 >= 0 && y0 < HH) ? 1.f : 0.f;
        float vy1 = (y1 >= 0 && y1 < HH) ? 1.f : 0.f;
        float vx0 = (x0 >= 0 && x0 < WW) ? 1.f : 0.f;
        float vx1 = (x1 >= 0 && x1 < WW) ? 1.f : 0.f;
        float w00 = (1.f - ly) * (1.f - lx) * m * vy0 * vx0;
        float w01 = (1.f - ly) * lx         * m * vy0 * vx1;
        float w10 = ly         * (1.f - lx) * m * vy1 * vx0;
        float w11 = ly         * lx         * m * vy1 * vx1;
        int yc0 = min(max(y0, 0), HH - 1), yc1 = min(max(y1, 0), HH - 1);
        int xc0 = min(max(x0, 0), WW - 1), xc1 = min(max(x1, 0), WW - 1);
        mwS[i] = make_float4(w00, w01, w10, w11);
        moS[i] = make_int4(yc0 * WW + xc0, yc0 * WW + xc1,
                           yc1 * WW + xc0, yc1 * WW + xc1);
    }

    const int p = t & 63;
    const float* xb = x + (size_t)(b * 64 + c0) * HW;   // wave-uniform base

    __syncthreads();   // meta visible

    // ---- prologue sample: tap 0 -> buffer 0 ----
    {
        float4 wv = mwS[0 * 64 + p];
        int4   ov = moS[0 * 64 + p];
        const float* pc = xb;
        #pragma unroll
        for (int i = 0; i < 16; i += 4) {
            float v0 = wv.x * pc[ov.x] + wv.y * pc[ov.y] + wv.z * pc[ov.z] + wv.w * pc[ov.w]; pc += HW;
            float v1 = wv.x * pc[ov.x] + wv.y * pc[ov.y] + wv.z * pc[ov.z] + wv.w * pc[ov.w]; pc += HW;
            float v2 = wv.x * pc[ov.x] + wv.y * pc[ov.y] + wv.z * pc[ov.z] + wv.w * pc[ov.w]; pc += HW;
            float v3 = wv.x * pc[ov.x] + wv.y * pc[ov.y] + wv.z * pc[ov.z] + wv.w * pc[ov.w]; pc += HW;
            uint2 u;
            u.x = (unsigned)f2bf(v0) | ((unsigned)f2bf(v1) << 16);
            u.y = (unsigned)f2bf(v2) | ((unsigned)f2bf(v3) << 16);
            *(uint2*)&s_tile[0][p][c0 + i] = u;
        }
    }
    __syncthreads();   // buffer 0 ready

    f32x4 acc[4];
    #pragma unroll
    for (int g = 0; g < 4; ++g) acc[g] = (f32x4){0.f, 0.f, 0.f, 0.f};

    // ---- main pipeline: 9 stages, 1 sync each ----
    #pragma unroll
    for (int s = 0; s < 9; ++s) {
        if (s < 8) {
            const int kn = s + 1;
            // prefetch next tap's weight fragments
            #pragma unroll
            for (int kf = 0; kf < 2; ++kf) {
                if (use_wt) {
                    wtf[kn & 1][kf] = *(const short8*)(wt + ((((kn * 2 + kf) * 4 + wv_id) * 64 + l) << 3));
                } else {
                    short8 f;
                    int co = cb + (l & 15);
                    int cbase = kf * 32 + (l >> 4) * 8;
                    #pragma unroll
                    for (int e = 0; e < 8; ++e) f[e] = (short)f2bf(wraw[(co * 64 + cbase + e) * 9 + kn]);
                    wtf[kn & 1][kf] = f;
                }
            }
            // sample next tap -> buffer (s+1)&1
            float4 wv = mwS[kn * 64 + p];
            int4   ov = moS[kn * 64 + p];
            const float* pc = xb;
            #pragma unroll
            for (int i = 0; i < 16; i += 4) {
                float v0 = wv.x * pc[ov.x] + wv.y * pc[ov.y] + wv.z * pc[ov.z] + wv.w * pc[ov.w]; pc += HW;
                float v1 = wv.x * pc[ov.x] + wv.y * pc[ov.y] + wv.z * pc[ov.z] + wv.w * pc[ov.w]; pc += HW;
                float v2 = wv.x * pc[ov.x] + wv.y * pc[ov.y] + wv.z * pc[ov.z] + wv.w * pc[ov.w]; pc += HW;
                float v3 = wv.x * pc[ov.x] + wv.y * pc[ov.y] + wv.z * pc[ov.z] + wv.w * pc[ov.w]; pc += HW;
                uint2 u;
                u.x = (unsigned)f2bf(v0) | ((unsigned)f2bf(v1) << 16);
                u.y = (unsigned)f2bf(v2) | ((unsigned)f2bf(v3) << 16);
                *(uint2*)&s_tile[kn & 1][p][c0 + i] = u;
            }
        }
        // MFMA on buffer s&1 with weights wtf[s&1]
        #pragma unroll
        for (int g = 0; g < 4; ++g) {
            const int prow = g * 16 + (l & 15);
            const unsigned short* rp = &s_tile[s & 1][prow][(l >> 4) * 8];
            union { short8 v; unsigned long long q[2]; } ua0, ua1;
            ua0.q[0] = *(const unsigned long long*)(rp);
            ua0.q[1] = *(const unsigned long long*)(rp + 4);
            ua1.q[0] = *(const unsigned long long*)(rp + 32);
            ua1.q[1] = *(const unsigned long long*)(rp + 36);
            acc[g] = __builtin_amdgcn_mfma_f32_16x16x32_bf16(ua0.v, wtf[s & 1][0], acc[g], 0, 0, 0);
            acc[g] = __builtin_amdgcn_mfma_f32_16x16x32_bf16(ua1.v, wtf[s & 1][1], acc[g], 0, 0, 0);
        }
        __syncthreads();
    }

    // ---- epilogue: transpose through LDS (meta region reused), coalesced stores ----
    const float bv = bias[cb + (l & 15)];
    #pragma unroll
    for (int g = 0; g < 4; ++g) {
        int co = cb + (l & 15);
        int pxb = g * 16 + (l >> 4) * 4;
        #pragma unroll
        for (int r = 0; r < 4; ++r)
            out_t[co * 68 + pxb + r] = acc[g][r] + bv;
    }
    __syncthreads();
    float* outb = out + (size_t)b * 64 * HW + (size_t)ho * WW + wo0;
    #pragma unroll
    for (int j = 0; j < 4; ++j) {
        int co  = (t >> 4) + j * 16;
        int px0 = (t & 15) << 2;
        float4 v = *(float4*)&out_t[co * 68 + px0];
        *(float4*)&outb[(size_t)co * HW + px0] = v;
    }
}

extern "C" void kernel_launch(void* const* d_in, const int* in_sizes, int n_in,
                              void* d_out, int out_size, void* d_ws, size_t ws_size,
                              hipStream_t stream) {
    const float* x    = (const float*)d_in[0];
    const float* off  = (const float*)d_in[1];
    const float* msk  = (const float*)d_in[2];
    const float* w    = (const float*)d_in[3];
    const float* bias = (const float*)d_in[4];
    float* out = (float*)d_out;

    const size_t packed_bytes = (size_t)9 * 2 * 4 * 64 * 8 * sizeof(unsigned short);
    int use_wt = (d_ws != nullptr && ws_size >= packed_bytes) ? 1 : 0;
    const unsigned short* wt = (const unsigned short*)d_ws;
    if (use_wt) {
        wtrans_kernel<<<144, 256, 0, stream>>>(w, (unsigned short*)d_ws);
    }
    deform_main<<<2048, 256, 0, stream>>>(x, off, msk, w, wt, bias, out, use_wt);
}

// Round 3
// 54.128 us; speedup vs baseline: 5.7881x; 3.9903x over previous
//
#include <hip/hip_runtime.h>

#define HH 128
#define WW 128
#define HW (HH*WW)
#define XT_BYTES ((size_t)8 * HW * 64 * 2)   // 16,777,216 bytes: x_t bf16 NHWC
#define WT_BYTES ((size_t)9 * 2 * 4 * 64 * 8 * 2)

typedef __attribute__((ext_vector_type(8))) short short8;
typedef __attribute__((ext_vector_type(4))) float f32x4;

static __device__ __forceinline__ unsigned short f2bf(float f) {
    unsigned int u = __float_as_uint(f);
    u += 0x7fffu + ((u >> 16) & 1u);
    return (unsigned short)(u >> 16);
}
static __device__ __forceinline__ float bf2f(unsigned short h) {
    return __uint_as_float((unsigned int)h << 16);
}

// weight (64,64,3,3) fp32 -> bf16 B-fragment layout wt[tap][kf][wave][lane][e]
__global__ void wtrans_kernel(const float* __restrict__ w, unsigned short* __restrict__ wt) {
    int i = blockIdx.x * 256 + threadIdx.x;
    if (i < 9 * 2 * 4 * 64 * 8) {
        int e  = i & 7;
        int l  = (i >> 3) & 63;
        int wv = (i >> 9) & 3;
        int kf = (i >> 11) & 1;
        int k  = i >> 12;
        int co = wv * 16 + (l & 15);
        int c  = kf * 32 + (l >> 4) * 8 + e;
        wt[i] = f2bf(w[(co * 64 + c) * 9 + k]);
    }
}

// x [8,64,128,128] f32 -> x_t [8,HW,64] bf16 (NHWC). Block: 64 hw x 64 ch.
__global__ __launch_bounds__(256) void xtrans_kernel(const float* __restrict__ x,
                                                     unsigned int* __restrict__ xt32) {
    __shared__ float tile[64][65];
    const int bid = blockIdx.x;
    const int b   = bid >> 8;
    const int hw0 = (bid & 255) << 6;
    const int t   = threadIdx.x;
    #pragma unroll
    for (int i = 0; i < 16; ++i) {
        int idx = (i << 8) + t;
        int c = idx >> 6, j = idx & 63;
        tile[c][j] = x[(size_t)(((b << 6) + c) << 14) + hw0 + j];
    }
    __syncthreads();
    #pragma unroll
    for (int i = 0; i < 8; ++i) {
        int idx = (i << 8) + t;
        int cp = idx & 31, hw = idx >> 5;
        unsigned u = (unsigned)f2bf(tile[2 * cp][hw]) | ((unsigned)f2bf(tile[2 * cp + 1][hw]) << 16);
        xt32[((size_t)((b << 14) + hw0 + hw) << 5) + cp] = u;
    }
}

// Fast path: one block = 64 px (half row) x 64 couts, 256 threads (4 waves).
__global__ __launch_bounds__(256, 4) void deform_nhwc(
    const unsigned short* __restrict__ xt,  // [8][HW][64] bf16
    const float* __restrict__ off,
    const float* __restrict__ msk,
    const unsigned short* __restrict__ wt,  // packed bf16 B-fragments
    const float* __restrict__ bias,
    float* __restrict__ out)
{
    __shared__ __align__(16) unsigned short s_tile[2][64][72];   // bf16 [px][ch]
    __shared__ __align__(16) unsigned char meta_mem[18432];
    float4* mwS = (float4*)meta_mem;              // [9][64] bilinear weights
    int4*   moS = (int4*)(meta_mem + 9216);       // [9][64] corner BYTE offsets into image
    float*  out_t = (float*)meta_mem;             // epilogue overlay [64][68]

    const int t   = threadIdx.x;
    const int bid = blockIdx.x;
    const int b   = bid & 7;                      // image <-> XCD affinity
    const int rem = bid >> 3;
    const int ho  = rem >> 1;
    const int wo0 = (rem & 1) << 6;
    const int l   = t & 63;
    const int wv_id = __builtin_amdgcn_readfirstlane(t >> 6);

    // ---- weight fragments, rotating 2-tap prefetch ----
    short8 wtf[2][2];
    #pragma unroll
    for (int kf = 0; kf < 2; ++kf)
        wtf[0][kf] = *(const short8*)(wt + (((kf * 4 + wv_id) * 64 + l) << 3));

    // ---- per-(tap,pixel) metadata ----
    for (int i = t; i < 9 * 64; i += 256) {
        int p = i & 63;
        int k = i >> 6;
        int wo = wo0 + p;
        int obase = ((b * 18 + 2 * k) * HH + ho) * WW + wo;
        float oy = off[obase];
        float ox = off[obase + HW];
        float m  = msk[((b * 9 + k) * HH + ho) * WW + wo];
        float py = oy + (float)(k / 3) + (float)(ho - 1);
        float px = ox + (float)(k % 3) + (float)(wo - 1);
        float fy = floorf(py), fx = floorf(px);
        float ly = py - fy,    lx = px - fx;
        int y0 = (int)fy, x0 = (int)fx;
        int y1 = y0 + 1,  x1 = x0 + 1;
        float vy0 = (y0 >= 0 && y0 < HH) ? 1.f : 0.f;
        float vy1 = (y1 >= 0 && y1 < HH) ? 1.f : 0.f;
        float vx0 = (x0 >= 0 && x0 < WW) ? 1.f : 0.f;
        float vx1 = (x1 >= 0 && x1 < WW) ? 1.f : 0.f;
        float w00 = (1.f - ly) * (1.f - lx) * m * vy0 * vx0;
        float w01 = (1.f - ly) * lx         * m * vy0 * vx1;
        float w10 = ly         * (1.f - lx) * m * vy1 * vx0;
        float w11 = ly         * lx         * m * vy1 * vx1;
        int yc0 = min(max(y0, 0), HH - 1), yc1 = min(max(y1, 0), HH - 1);
        int xc0 = min(max(x0, 0), WW - 1), xc1 = min(max(x1, 0), WW - 1);
        mwS[i] = make_float4(w00, w01, w10, w11);
        moS[i] = make_int4((yc0 * WW + xc0) << 7, (yc0 * WW + xc1) << 7,
                           (yc1 * WW + xc0) << 7, (yc1 * WW + xc1) << 7);
    }

    const char* ib = (const char*)xt + (size_t)b * HW * 128;   // image base (bytes)
    const int ch0 = (l & 7) << 3;        // 8 channels per lane
    const int ch2 = ch0 << 1;            // byte offset of those channels

    __syncthreads();   // meta visible

    // sampling for tap k into buffer bb
    auto sample_tap = [&](int k, int bb) {
        #pragma unroll
        for (int r = 0; r < 2; ++r) {
            int px = (wv_id << 4) + (r << 3) + (l >> 3);
            int4   ob = moS[k * 64 + px];
            float4 ww = mwS[k * 64 + px];
            short8 c00 = *(const short8*)(ib + ob.x + ch2);
            short8 c01 = *(const short8*)(ib + ob.y + ch2);
            short8 c10 = *(const short8*)(ib + ob.z + ch2);
            short8 c11 = *(const short8*)(ib + ob.w + ch2);
            unsigned u[4];
            #pragma unroll
            for (int e = 0; e < 8; e += 2) {
                float v0 = ww.x * bf2f((unsigned short)c00[e])   + ww.y * bf2f((unsigned short)c01[e])
                         + ww.z * bf2f((unsigned short)c10[e])   + ww.w * bf2f((unsigned short)c11[e]);
                float v1 = ww.x * bf2f((unsigned short)c00[e+1]) + ww.y * bf2f((unsigned short)c01[e+1])
                         + ww.z * bf2f((unsigned short)c10[e+1]) + ww.w * bf2f((unsigned short)c11[e+1]);
                u[e >> 1] = (unsigned)f2bf(v0) | ((unsigned)f2bf(v1) << 16);
            }
            uint4 uv = make_uint4(u[0], u[1], u[2], u[3]);
            *(uint4*)&s_tile[bb][px][ch0] = uv;
        }
    };

    // ---- prologue: tap 0 -> buffer 0 ----
    sample_tap(0, 0);
    __syncthreads();

    f32x4 acc[4];
    #pragma unroll
    for (int g = 0; g < 4; ++g) acc[g] = (f32x4){0.f, 0.f, 0.f, 0.f};

    // ---- 9 stages, 1 sync each ----
    #pragma unroll
    for (int s = 0; s < 9; ++s) {
        if (s < 8) {
            const int kn = s + 1;
            #pragma unroll
            for (int kf = 0; kf < 2; ++kf)
                wtf[kn & 1][kf] = *(const short8*)(wt + ((((kn * 2 + kf) * 4 + wv_id) * 64 + l) << 3));
            sample_tap(kn, kn & 1);
        }
        #pragma unroll
        for (int g = 0; g < 4; ++g) {
            const int prow = g * 16 + (l & 15);
            const unsigned short* rp = &s_tile[s & 1][prow][(l >> 4) * 8];
            union { short8 v; unsigned long long q[2]; } ua0, ua1;
            ua0.q[0] = *(const unsigned long long*)(rp);
            ua0.q[1] = *(const unsigned long long*)(rp + 4);
            ua1.q[0] = *(const unsigned long long*)(rp + 32);
            ua1.q[1] = *(const unsigned long long*)(rp + 36);
            acc[g] = __builtin_amdgcn_mfma_f32_16x16x32_bf16(ua0.v, wtf[s & 1][0], acc[g], 0, 0, 0);
            acc[g] = __builtin_amdgcn_mfma_f32_16x16x32_bf16(ua1.v, wtf[s & 1][1], acc[g], 0, 0, 0);
        }
        __syncthreads();
    }

    // ---- epilogue: transpose through LDS, coalesced float4 stores ----
    const int cb = wv_id << 4;
    const float bv = bias[cb + (l & 15)];
    #pragma unroll
    for (int g = 0; g < 4; ++g) {
        int co = cb + (l & 15);
        int pxb = g * 16 + (l >> 4) * 4;
        #pragma unroll
        for (int r = 0; r < 4; ++r)
            out_t[co * 68 + pxb + r] = acc[g][r] + bv;
    }
    __syncthreads();
    float* outb = out + (size_t)b * 64 * HW + (size_t)ho * WW + wo0;
    #pragma unroll
    for (int j = 0; j < 4; ++j) {
        int co  = (t >> 4) + j * 16;
        int px0 = (t & 15) << 2;
        float4 v = *(float4*)&out_t[co * 68 + px0];
        *(float4*)&outb[(size_t)co * HW + px0] = v;
    }
}

// -------- fallback (round-2 kernel, NCHW gather, raw weights) --------
__global__ __launch_bounds__(256, 4) void deform_fallback(
    const float* __restrict__ x, const float* __restrict__ off,
    const float* __restrict__ msk, const float* __restrict__ wraw,
    const float* __restrict__ bias, float* __restrict__ out)
{
    __shared__ unsigned short s_tile[2][64][68];
    __shared__ __align__(16) unsigned char meta_mem[18432];
    float4* mwS = (float4*)meta_mem;
    int4*   moS = (int4*)(meta_mem + 9216);
    float*  out_t = (float*)meta_mem;

    const int t   = threadIdx.x;
    const int bid = blockIdx.x;
    const int b   = bid & 7;
    const int rem = bid >> 3;
    const int ho  = rem >> 1;
    const int wo0 = (rem & 1) << 6;
    const int l   = t & 63;
    const int wv_id = __builtin_amdgcn_readfirstlane(t >> 6);
    const int c0  = wv_id << 4;
    const int cb  = wv_id << 4;

    short8 wtf[2][2];
    #pragma unroll
    for (int kf = 0; kf < 2; ++kf) {
        short8 f;
        int co = cb + (l & 15);
        int cbase = kf * 32 + (l >> 4) * 8;
        #pragma unroll
        for (int e = 0; e < 8; ++e) f[e] = (short)f2bf(wraw[(co * 64 + cbase + e) * 9 + 0]);
        wtf[0][kf] = f;
    }

    for (int i = t; i < 9 * 64; i += 256) {
        int p = i & 63;
        int k = i >> 6;
        int wo = wo0 + p;
        int obase = ((b * 18 + 2 * k) * HH + ho) * WW + wo;
        float oy = off[obase];
        float ox = off[obase + HW];
        float m  = msk[((b * 9 + k) * HH + ho) * WW + wo];
        float py = oy + (float)(k / 3) + (float)(ho - 1);
        float px = ox + (float)(k % 3) + (float)(wo - 1);
        float fy = floorf(py), fx = floorf(px);
        float ly = py - fy,    lx = px - fx;
        int y0 = (int)fy, x0 = (int)fx;
        int y1 = y0 + 1,  x1 = x0 + 1;
        float vy0 = (y0 >= 0 && y0 < HH) ? 1.f : 0.f;
        float vy1 = (y1 >= 0 && y1 < HH) ? 1.f : 0.f;
        float vx0 = (x0 >= 0 && x0 < WW) ? 1.f : 0.f;
        float vx1 = (x1 >= 0 && x1 < WW) ? 1.f : 0.f;
        float w00 = (1.f - ly) * (1.f - lx) * m * vy0 * vx0;
        float w01 = (1.f - ly) * lx         * m * vy0 * vx1;
        float w10 = ly         * (1.f - lx) * m * vy1 * vx0;
        float w11 = ly         * lx         * m * vy1 * vx1;
        int yc0 = min(max(y0, 0), HH - 1), yc1 = min(max(y1, 0), HH - 1);
        int xc0 = min(max(x0, 0), WW - 1), xc1 = min(max(x1, 0), WW - 1);
        mwS[i] = make_float4(w00, w01, w10, w11);
        moS[i] = make_int4(yc0 * WW + xc0, yc0 * WW + xc1,
                           yc1 * WW + xc0, yc1 * WW + xc1);
    }

    const int p = t & 63;
    const float* xb = x + (size_t)(b * 64 + c0) * HW;
    __syncthreads();

    {
        float4 wv = mwS[p];
        int4   ov = moS[p];
        const float* pc = xb;
        #pragma unroll
        for (int i = 0; i < 16; i += 4) {
            float v0 = wv.x * pc[ov.x] + wv.y * pc[ov.y] + wv.z * pc[ov.z] + wv.w * pc[ov.w]; pc += HW;
            float v1 = wv.x * pc[ov.x] + wv.y * pc[ov.y] + wv.z * pc[ov.z] + wv.w * pc[ov.w]; pc += HW;
            float v2 = wv.x * pc[ov.x] + wv.y * pc[ov.y] + wv.z * pc[ov.z] + wv.w * pc[ov.w]; pc += HW;
            float v3 = wv.x * pc[ov.x] + wv.y * pc[ov.y] + wv.z * pc[ov.z] + wv.w * pc[ov.w]; pc += HW;
            uint2 u;
            u.x = (unsigned)f2bf(v0) | ((unsigned)f2bf(v1) << 16);
            u.y = (unsigned)f2bf(v2) | ((unsigned)f2bf(v3) << 16);
            *(uint2*)&s_tile[0][p][c0 + i] = u;
        }
    }
    __syncthreads();

    f32x4 acc[4];
    #pragma unroll
    for (int g = 0; g < 4; ++g) acc[g] = (f32x4){0.f, 0.f, 0.f, 0.f};

    #pragma unroll
    for (int s = 0; s < 9; ++s) {
        if (s < 8) {
            const int kn = s + 1;
            #pragma unroll
            for (int kf = 0; kf < 2; ++kf) {
                short8 f;
                int co = cb + (l & 15);
                int cbase = kf * 32 + (l >> 4) * 8;
                #pragma unroll
                for (int e = 0; e < 8; ++e) f[e] = (short)f2bf(wraw[(co * 64 + cbase + e) * 9 + kn]);
                wtf[kn & 1][kf] = f;
            }
            float4 wv = mwS[kn * 64 + p];
            int4   ov = moS[kn * 64 + p];
            const float* pc = xb;
            #pragma unroll
            for (int i = 0; i < 16; i += 4) {
                float v0 = wv.x * pc[ov.x] + wv.y * pc[ov.y] + wv.z * pc[ov.z] + wv.w * pc[ov.w]; pc += HW;
                float v1 = wv.x * pc[ov.x] + wv.y * pc[ov.y] + wv.z * pc[ov.z] + wv.w * pc[ov.w]; pc += HW;
                float v2 = wv.x * pc[ov.x] + wv.y * pc[ov.y] + wv.z * pc[ov.z] + wv.w * pc[ov.w]; pc += HW;
                float v3 = wv.x * pc[ov.x] + wv.y * pc[ov.y] + wv.z * pc[ov.z] + wv.w * pc[ov.w]; pc += HW;
                uint2 u;
                u.x = (unsigned)f2bf(v0) | ((unsigned)f2bf(v1) << 16);
                u.y = (unsigned)f2bf(v2) | ((unsigned)f2bf(v3) << 16);
                *(uint2*)&s_tile[kn & 1][p][c0 + i] = u;
            }
        }
        #pragma unroll
        for (int g = 0; g < 4; ++g) {
            const int prow = g * 16 + (l & 15);
            const unsigned short* rp = &s_tile[s & 1][prow][(l >> 4) * 8];
            union { short8 v; unsigned long long q[2]; } ua0, ua1;
            ua0.q[0] = *(const unsigned long long*)(rp);
            ua0.q[1] = *(const unsigned long long*)(rp + 4);
            ua1.q[0] = *(const unsigned long long*)(rp + 32);
            ua1.q[1] = *(const unsigned long long*)(rp + 36);
            acc[g] = __builtin_amdgcn_mfma_f32_16x16x32_bf16(ua0.v, wtf[s & 1][0], acc[g], 0, 0, 0);
            acc[g] = __builtin_amdgcn_mfma_f32_16x16x32_bf16(ua1.v, wtf[s & 1][1], acc[g], 0, 0, 0);
        }
        __syncthreads();
    }

    const float bv = bias[cb + (l & 15)];
    #pragma unroll
    for (int g = 0; g < 4; ++g) {
        int co = cb + (l & 15);
        int pxb = g * 16 + (l >> 4) * 4;
        #pragma unroll
        for (int r = 0; r < 4; ++r)
            out_t[co * 68 + pxb + r] = acc[g][r] + bv;
    }
    __syncthreads();
    float* outb = out + (size_t)b * 64 * HW + (size_t)ho * WW + wo0;
    #pragma unroll
    for (int j = 0; j < 4; ++j) {
        int co  = (t >> 4) + j * 16;
        int px0 = (t & 15) << 2;
        float4 v = *(float4*)&out_t[co * 68 + px0];
        *(float4*)&outb[(size_t)co * HW + px0] = v;
    }
}

extern "C" void kernel_launch(void* const* d_in, const int* in_sizes, int n_in,
                              void* d_out, int out_size, void* d_ws, size_t ws_size,
                              hipStream_t stream) {
    const float* x    = (const float*)d_in[0];
    const float* off  = (const float*)d_in[1];
    const float* msk  = (const float*)d_in[2];
    const float* w    = (const float*)d_in[3];
    const float* bias = (const float*)d_in[4];
    float* out = (float*)d_out;

    const size_t need = XT_BYTES + WT_BYTES;
    if (d_ws != nullptr && ws_size >= need) {
        unsigned int*   xt32 = (unsigned int*)d_ws;
        unsigned short* wt   = (unsigned short*)((char*)d_ws + XT_BYTES);
        xtrans_kernel<<<2048, 256, 0, stream>>>(x, xt32);
        wtrans_kernel<<<144, 256, 0, stream>>>(w, wt);
        deform_nhwc<<<2048, 256, 0, stream>>>((const unsigned short*)xt32, off, msk, wt, bias, out);
    } else {
        deform_fallback<<<2048, 256, 0, stream>>>(x, off, msk, w, bias, out);
    }
}

// Round 4
// 52.728 us; speedup vs baseline: 5.9418x; 1.0265x over previous
//
#include <hip/hip_runtime.h>
#include <hip/hip_fp16.h>

#define HH 128
#define WW 128
#define HW (HH*WW)
#define XT_BYTES ((size_t)8 * HW * 64 * 2)   // x_t bf16 NHWC
#define WT_BYTES ((size_t)9 * 2 * 4 * 64 * 8 * 2)

typedef __attribute__((ext_vector_type(8))) short short8;
typedef __attribute__((ext_vector_type(4))) float f32x4;

static __device__ __forceinline__ unsigned short f2bf(float f) {
    unsigned int u = __float_as_uint(f);
    u += 0x7fffu + ((u >> 16) & 1u);
    return (unsigned short)(u >> 16);
}
static __device__ __forceinline__ float bf2f(unsigned short h) {
    return __uint_as_float((unsigned int)h << 16);
}
static __device__ __forceinline__ float blo(unsigned int u) {   // low bf16 -> f32
    return __uint_as_float(u << 16);
}
static __device__ __forceinline__ float bhi(unsigned int u) {   // high bf16 -> f32
    return __uint_as_float(u & 0xffff0000u);
}

// weight (64,64,3,3) fp32 -> bf16 B-fragment layout wt[tap][kf][wave][lane][e]
__global__ void wtrans_kernel(const float* __restrict__ w, unsigned short* __restrict__ wt) {
    int i = blockIdx.x * 256 + threadIdx.x;
    if (i < 9 * 2 * 4 * 64 * 8) {
        int e  = i & 7;
        int l  = (i >> 3) & 63;
        int wv = (i >> 9) & 3;
        int kf = (i >> 11) & 1;
        int k  = i >> 12;
        int co = wv * 16 + (l & 15);
        int c  = kf * 32 + (l >> 4) * 8 + e;
        wt[i] = f2bf(w[(co * 64 + c) * 9 + k]);
    }
}

// x [8,64,128,128] f32 -> x_t [8,HW,64] bf16 (NHWC). Block: 64 hw x 64 ch.
__global__ __launch_bounds__(256) void xtrans_kernel(const float* __restrict__ x,
                                                     unsigned int* __restrict__ xt32) {
    __shared__ float tile[64][65];
    const int bid = blockIdx.x;
    const int b   = bid >> 8;
    const int hw0 = (bid & 255) << 6;
    const int t   = threadIdx.x;
    #pragma unroll
    for (int i = 0; i < 16; ++i) {
        int idx = (i << 8) + t;
        int c = idx >> 6, j = idx & 63;
        tile[c][j] = x[(size_t)(((b << 6) + c) << 14) + hw0 + j];
    }
    __syncthreads();
    #pragma unroll
    for (int i = 0; i < 8; ++i) {
        int idx = (i << 8) + t;
        int cp = idx & 31, hw = idx >> 5;
        unsigned u = (unsigned)f2bf(tile[2 * cp][hw]) | ((unsigned)f2bf(tile[2 * cp + 1][hw]) << 16);
        xt32[((size_t)((b << 14) + hw0 + hw) << 5) + cp] = u;
    }
}

// Fast path: one block = 64 px (half row) x 64 couts, 256 threads (4 waves).
// LDS: swizzled double-buffered bf16 sample tile (16 KB) + meta (13.8 KB) ~ 29.5 KB -> 5 blocks/CU.
__global__ __launch_bounds__(256, 5) void deform_nhwc(
    const unsigned short* __restrict__ xt,  // [8][HW][64] bf16
    const float* __restrict__ off,
    const float* __restrict__ msk,
    const unsigned short* __restrict__ wt,  // packed bf16 B-fragments
    const float* __restrict__ bias,
    float* __restrict__ out)
{
    // [0,16384): two 8 KB sample buffers, XOR-swizzled [64 px][64 ch] bf16
    // [16384,25600): moS int4 corner byte-offsets [9*64]
    // [25600,30208): mwH packed fp16 bilinear weight pairs [9*64]
    // epilogue: [0,16384) reused as swizzled fp32 out_t [64 co][64 px]
    __shared__ __align__(16) unsigned char smem[30208];
    int4*  moS = (int4*)(smem + 16384);
    uint2* mwH = (uint2*)(smem + 25600);

    const int t   = threadIdx.x;
    const int bid = blockIdx.x;
    const int b   = bid & 7;            // image <-> XCD affinity
    const int rem = bid >> 3;
    const int ho  = rem >> 1;
    const int wo0 = (rem & 1) << 6;
    const int l   = t & 63;
    const int wv_id = __builtin_amdgcn_readfirstlane(t >> 6);

    // ---- B-fragments: rotating 2-tap prefetch in registers ----
    short8 wtf[2][2];
    #pragma unroll
    for (int kf = 0; kf < 2; ++kf)
        wtf[0][kf] = *(const short8*)(wt + (((kf * 4 + wv_id) * 64 + l) << 3));

    // ---- per-(tap,pixel) metadata ----
    for (int i = t; i < 9 * 64; i += 256) {
        int p = i & 63;
        int k = i >> 6;
        int wo = wo0 + p;
        int obase = ((b * 18 + 2 * k) * HH + ho) * WW + wo;
        float oy = off[obase];
        float ox = off[obase + HW];
        float m  = msk[((b * 9 + k) * HH + ho) * WW + wo];
        float py = oy + (float)(k / 3) + (float)(ho - 1);
        float px = ox + (float)(k % 3) + (float)(wo - 1);
        float fy = floorf(py), fx = floorf(px);
        float ly = py - fy,    lx = px - fx;
        int y0 = (int)fy, x0 = (int)fx;
        int y1 = y0 + 1,  x1 = x0 + 1;
        float vy0 = (y0 >= 0 && y0 < HH) ? 1.f : 0.f;
        float vy1 = (y1 >= 0 && y1 < HH) ? 1.f : 0.f;
        float vx0 = (x0 >= 0 && x0 < WW) ? 1.f : 0.f;
        float vx1 = (x1 >= 0 && x1 < WW) ? 1.f : 0.f;
        float w00 = (1.f - ly) * (1.f - lx) * m * vy0 * vx0;
        float w01 = (1.f - ly) * lx         * m * vy0 * vx1;
        float w10 = ly         * (1.f - lx) * m * vy1 * vx0;
        float w11 = ly         * lx         * m * vy1 * vx1;
        int yc0 = min(max(y0, 0), HH - 1), yc1 = min(max(y1, 0), HH - 1);
        int xc0 = min(max(x0, 0), WW - 1), xc1 = min(max(x1, 0), WW - 1);
        moS[i] = make_int4((yc0 * WW + xc0) << 7, (yc0 * WW + xc1) << 7,
                           (yc1 * WW + xc0) << 7, (yc1 * WW + xc1) << 7);
        __half2 hA = __floats2half2_rn(w00, w01);
        __half2 hB = __floats2half2_rn(w10, w11);
        mwH[i] = make_uint2(*(unsigned int*)&hA, *(unsigned int*)&hB);
    }

    const char* ib = (const char*)xt + (size_t)b * HW * 128;   // image base (bytes)
    const int chb  = (l & 7) << 4;                 // byte offset of this lane's 8 channels
    const int px0_ = (wv_id << 4) + (l >> 3);      // r=0 pixel
    int st_woff[2];
    st_woff[0] = px0_ * 128 + (chb ^ ((px0_ & 7) << 4));
    st_woff[1] = st_woff[0] + 8 * 128;             // (px0_+8)&7 == px0_&7
    const int lq = (l >> 4) << 4;                  // fragment col-byte base
    const int sw = (l & 7) << 4;                   // read-side swizzle (prow&7 == l&7)

    __syncthreads();   // meta visible

    auto sample_tap = [&](int k, unsigned char* dst) {
        #pragma unroll
        for (int r = 0; r < 2; ++r) {
            const int px = px0_ + (r << 3);
            int4   ob = moS[k * 64 + px];
            uint2  wp = mwH[k * 64 + px];
            float2 wA = __half22float2(*(const __half2*)&wp.x);   // w00, w01
            float2 wB = __half22float2(*(const __half2*)&wp.y);   // w10, w11
            uint4 c00 = *(const uint4*)(ib + (ob.x + chb));
            uint4 c01 = *(const uint4*)(ib + (ob.y + chb));
            uint4 c10 = *(const uint4*)(ib + (ob.z + chb));
            uint4 c11 = *(const uint4*)(ib + (ob.w + chb));
            uint4 uv;
            #define CMB(dst_, a0, a1, a2, a3) {                                         \
                float vlo = wA.x*blo(a0) + wA.y*blo(a1) + wB.x*blo(a2) + wB.y*blo(a3);  \
                float vhi = wA.x*bhi(a0) + wA.y*bhi(a1) + wB.x*bhi(a2) + wB.y*bhi(a3);  \
                dst_ = __builtin_amdgcn_perm(__float_as_uint(vhi) + 0x8000u,            \
                                             __float_as_uint(vlo) + 0x8000u, 0x07060302u); }
            CMB(uv.x, c00.x, c01.x, c10.x, c11.x);
            CMB(uv.y, c00.y, c01.y, c10.y, c11.y);
            CMB(uv.z, c00.z, c01.z, c10.z, c11.z);
            CMB(uv.w, c00.w, c01.w, c10.w, c11.w);
            #undef CMB
            *(uint4*)(dst + st_woff[r]) = uv;
        }
    };

    // ---- prologue: tap 0 -> buffer 0 ----
    sample_tap(0, smem);
    __syncthreads();

    f32x4 acc[4];
    #pragma unroll
    for (int g = 0; g < 4; ++g) acc[g] = (f32x4){0.f, 0.f, 0.f, 0.f};

    // ---- 9 stages, 1 sync each ----
    #pragma unroll
    for (int s = 0; s < 9; ++s) {
        if (s < 8) {
            const int kn = s + 1;
            #pragma unroll
            for (int kf = 0; kf < 2; ++kf)
                wtf[kn & 1][kf] = *(const short8*)(wt + ((((kn * 2 + kf) * 4 + wv_id) * 64 + l) << 3));
            sample_tap(kn, smem + ((kn & 1) << 13));
        }
        const unsigned char* rb = smem + ((s & 1) << 13);
        #pragma unroll
        for (int g = 0; g < 4; ++g) {
            const int prow = g * 16 + (l & 15);
            short8 a0 = *(const short8*)(rb + prow * 128 + (lq ^ sw));
            short8 a1 = *(const short8*)(rb + prow * 128 + ((64 + lq) ^ sw));
            acc[g] = __builtin_amdgcn_mfma_f32_16x16x32_bf16(a0, wtf[s & 1][0], acc[g], 0, 0, 0);
            acc[g] = __builtin_amdgcn_mfma_f32_16x16x32_bf16(a1, wtf[s & 1][1], acc[g], 0, 0, 0);
        }
        __syncthreads();
    }

    // ---- epilogue: swizzled transpose through LDS (sample buffers reused), coalesced stores ----
    float* out_t = (float*)smem;   // [64 co][256 B rows], XOR-swizzled
    const int co_e = (wv_id << 4) + (l & 15);
    const float bv = bias[co_e];
    const int swE = (co_e & 15) << 4;
    #pragma unroll
    for (int g = 0; g < 4; ++g) {
        int pxb = (g << 6) + ((l >> 4) << 4);   // byte col of pixel group
        float4 v = make_float4(acc[g][0] + bv, acc[g][1] + bv, acc[g][2] + bv, acc[g][3] + bv);
        *(float4*)((unsigned char*)out_t + co_e * 256 + (pxb ^ swE)) = v;
    }
    __syncthreads();
    float* outb = out + (size_t)b * 64 * HW + (size_t)ho * WW + wo0;
    #pragma unroll
    for (int j = 0; j < 4; ++j) {
        int co   = (t >> 4) + (j << 4);
        int colb = (t & 15) << 4;
        float4 v = *(const float4*)((const unsigned char*)out_t + co * 256 + (colb ^ ((co & 15) << 4)));
        *(float4*)&outb[(size_t)co * HW + ((t & 15) << 2)] = v;
    }
}

// -------- fallback (NCHW gather, raw weights) for tiny workspace --------
__global__ __launch_bounds__(256, 4) void deform_fallback(
    const float* __restrict__ x, const float* __restrict__ off,
    const float* __restrict__ msk, const float* __restrict__ wraw,
    const float* __restrict__ bias, float* __restrict__ out)
{
    __shared__ unsigned short s_tile[2][64][68];
    __shared__ __align__(16) unsigned char meta_mem[18432];
    float4* mwS = (float4*)meta_mem;
    int4*   moS = (int4*)(meta_mem + 9216);
    float*  out_t = (float*)meta_mem;

    const int t   = threadIdx.x;
    const int bid = blockIdx.x;
    const int b   = bid & 7;
    const int rem = bid >> 3;
    const int ho  = rem >> 1;
    const int wo0 = (rem & 1) << 6;
    const int l   = t & 63;
    const int wv_id = __builtin_amdgcn_readfirstlane(t >> 6);
    const int c0  = wv_id << 4;
    const int cb  = wv_id << 4;

    short8 wtf[2][2];
    #pragma unroll
    for (int kf = 0; kf < 2; ++kf) {
        short8 f;
        int co = cb + (l & 15);
        int cbase = kf * 32 + (l >> 4) * 8;
        #pragma unroll
        for (int e = 0; e < 8; ++e) f[e] = (short)f2bf(wraw[(co * 64 + cbase + e) * 9 + 0]);
        wtf[0][kf] = f;
    }

    for (int i = t; i < 9 * 64; i += 256) {
        int p = i & 63;
        int k = i >> 6;
        int wo = wo0 + p;
        int obase = ((b * 18 + 2 * k) * HH + ho) * WW + wo;
        float oy = off[obase];
        float ox = off[obase + HW];
        float m  = msk[((b * 9 + k) * HH + ho) * WW + wo];
        float py = oy + (float)(k / 3) + (float)(ho - 1);
        float px = ox + (float)(k % 3) + (float)(wo - 1);
        float fy = floorf(py), fx = floorf(px);
        float ly = py - fy,    lx = px - fx;
        int y0 = (int)fy, x0 = (int)fx;
        int y1 = y0 + 1,  x1 = x0 + 1;
        float vy0 = (y0 >= 0 && y0 < HH) ? 1.f : 0.f;
        float vy1 = (y1 >= 0 && y1 < HH) ? 1.f : 0.f;
        float vx0 = (x0 >= 0 && x0 < WW) ? 1.f : 0.f;
        float vx1 = (x1 >= 0 && x1 < WW) ? 1.f : 0.f;
        float w00 = (1.f - ly) * (1.f - lx) * m * vy0 * vx0;
        float w01 = (1.f - ly) * lx         * m * vy0 * vx1;
        float w10 = ly         * (1.f - lx) * m * vy1 * vx0;
        float w11 = ly         * lx         * m * vy1 * vx1;
        int yc0 = min(max(y0, 0), HH - 1), yc1 = min(max(y1, 0), HH - 1);
        int xc0 = min(max(x0, 0), WW - 1), xc1 = min(max(x1, 0), WW - 1);
        mwS[i] = make_float4(w00, w01, w10, w11);
        moS[i] = make_int4(yc0 * WW + xc0, yc0 * WW + xc1,
                           yc1 * WW + xc0, yc1 * WW + xc1);
    }

    const int p = t & 63;
    const float* xb = x + (size_t)(b * 64 + c0) * HW;
    __syncthreads();

    {
        float4 wv = mwS[p];
        int4   ov = moS[p];
        const float* pc = xb;
        #pragma unroll
        for (int i = 0; i < 16; i += 4) {
            float v0 = wv.x * pc[ov.x] + wv.y * pc[ov.y] + wv.z * pc[ov.z] + wv.w * pc[ov.w]; pc += HW;
            float v1 = wv.x * pc[ov.x] + wv.y * pc[ov.y] + wv.z * pc[ov.z] + wv.w * pc[ov.w]; pc += HW;
            float v2 = wv.x * pc[ov.x] + wv.y * pc[ov.y] + wv.z * pc[ov.z] + wv.w * pc[ov.w]; pc += HW;
            float v3 = wv.x * pc[ov.x] + wv.y * pc[ov.y] + wv.z * pc[ov.z] + wv.w * pc[ov.w]; pc += HW;
            uint2 u;
            u.x = (unsigned)f2bf(v0) | ((unsigned)f2bf(v1) << 16);
            u.y = (unsigned)f2bf(v2) | ((unsigned)f2bf(v3) << 16);
            *(uint2*)&s_tile[0][p][c0 + i] = u;
        }
    }
    __syncthreads();

    f32x4 acc[4];
    #pragma unroll
    for (int g = 0; g < 4; ++g) acc[g] = (f32x4){0.f, 0.f, 0.f, 0.f};

    #pragma unroll
    for (int s = 0; s < 9; ++s) {
        if (s < 8) {
            const int kn = s + 1;
            #pragma unroll
            for (int kf = 0; kf < 2; ++kf) {
                short8 f;
                int co = cb + (l & 15);
                int cbase = kf * 32 + (l >> 4) * 8;
                #pragma unroll
                for (int e = 0; e < 8; ++e) f[e] = (short)f2bf(wraw[(co * 64 + cbase + e) * 9 + kn]);
                wtf[kn & 1][kf] = f;
            }
            float4 wv = mwS[kn * 64 + p];
            int4   ov = moS[kn * 64 + p];
            const float* pc = xb;
            #pragma unroll
            for (int i = 0; i < 16; i += 4) {
                float v0 = wv.x * pc[ov.x] + wv.y * pc[ov.y] + wv.z * pc[ov.z] + wv.w * pc[ov.w]; pc += HW;
                float v1 = wv.x * pc[ov.x] + wv.y * pc[ov.y] + wv.z * pc[ov.z] + wv.w * pc[ov.w]; pc += HW;
                float v2 = wv.x * pc[ov.x] + wv.y * pc[ov.y] + wv.z * pc[ov.z] + wv.w * pc[ov.w]; pc += HW;
                float v3 = wv.x * pc[ov.x] + wv.y * pc[ov.y] + wv.z * pc[ov.z] + wv.w * pc[ov.w]; pc += HW;
                uint2 u;
                u.x = (unsigned)f2bf(v0) | ((unsigned)f2bf(v1) << 16);
                u.y = (unsigned)f2bf(v2) | ((unsigned)f2bf(v3) << 16);
                *(uint2*)&s_tile[kn & 1][p][c0 + i] = u;
            }
        }
        #pragma unroll
        for (int g = 0; g < 4; ++g) {
            const int prow = g * 16 + (l & 15);
            const unsigned short* rp = &s_tile[s & 1][prow][(l >> 4) * 8];
            union { short8 v; unsigned long long q[2]; } ua0, ua1;
            ua0.q[0] = *(const unsigned long long*)(rp);
            ua0.q[1] = *(const unsigned long long*)(rp + 4);
            ua1.q[0] = *(const unsigned long long*)(rp + 32);
            ua1.q[1] = *(const unsigned long long*)(rp + 36);
            acc[g] = __builtin_amdgcn_mfma_f32_16x16x32_bf16(ua0.v, wtf[s & 1][0], acc[g], 0, 0, 0);
            acc[g] = __builtin_amdgcn_mfma_f32_16x16x32_bf16(ua1.v, wtf[s & 1][1], acc[g], 0, 0, 0);
        }
        __syncthreads();
    }

    const float bv = bias[cb + (l & 15)];
    #pragma unroll
    for (int g = 0; g < 4; ++g) {
        int co = cb + (l & 15);
        int pxb = g * 16 + (l >> 4) * 4;
        #pragma unroll
        for (int r = 0; r < 4; ++r)
            out_t[co * 68 + pxb + r] = acc[g][r] + bv;
    }
    __syncthreads();
    float* outb = out + (size_t)b * 64 * HW + (size_t)ho * WW + wo0;
    #pragma unroll
    for (int j = 0; j < 4; ++j) {
        int co  = (t >> 4) + j * 16;
        int px0 = (t & 15) << 2;
        float4 v = *(float4*)&out_t[co * 68 + px0];
        *(float4*)&outb[(size_t)co * HW + px0] = v;
    }
}

extern "C" void kernel_launch(void* const* d_in, const int* in_sizes, int n_in,
                              void* d_out, int out_size, void* d_ws, size_t ws_size,
                              hipStream_t stream) {
    const float* x    = (const float*)d_in[0];
    const float* off  = (const float*)d_in[1];
    const float* msk  = (const float*)d_in[2];
    const float* w    = (const float*)d_in[3];
    const float* bias = (const float*)d_in[4];
    float* out = (float*)d_out;

    const size_t need = XT_BYTES + WT_BYTES;
    if (d_ws != nullptr && ws_size >= need) {
        unsigned int*   xt32 = (unsigned int*)d_ws;
        unsigned short* wt   = (unsigned short*)((char*)d_ws + XT_BYTES);
        xtrans_kernel<<<2048, 256, 0, stream>>>(x, xt32);
        wtrans_kernel<<<144, 256, 0, stream>>>(w, wt);
        deform_nhwc<<<2048, 256, 0, stream>>>((const unsigned short*)xt32, off, msk, wt, bias, out);
    } else {
        deform_fallback<<<2048, 256, 0, stream>>>(x, off, msk, w, bias, out);
    }
}